// Round 8
// baseline (6414.693 us; speedup 1.0000x reference)
//
#include <hip/hip_runtime.h>
#include <hip/hip_fp16.h>
#include <cstdint>
#include <cstddef>

// ---------------------------------------------------------------------------
// CNN (conv1+pool, conv2+pool) -> seq [256][256][32]
// NTM scan: 128 blocks x 1024 threads, 2 batch/block, 1 block/CU.
// Pipelined schedule per iteration i (5 barriers):
//   E: LSTM step i (zpart sum + WrT*rp reads-term) -> h_i ; x_{i+1} prefetch
//   A: P3 head GEMM(h_i)      || issue weight chunk0 (z_{i+1})
//   B: P4 addressing          || consume chunk0 (dot2), issue chunk1
//   C: P5 read+erase/add -> rp|| consume chunk1, issue chunk2
//   D: consume chunk2 + 6 LDS-resident pairs + write zpart (= z_{i+1})
// Weight loads are issued one full region before use (weights are constant),
// so no phase ever sits on a cold load burst. Reads enter z via WrT*rp only.
// ci pair slots (u32): [x:0..15][h:16..143], 144 pairs total.
// ---------------------------------------------------------------------------

#define MW    20
#define NLOC  128
#define ZC    1024
#define PC    92
#define CLIPV 20.0f

__device__ __forceinline__ float sigmoidf_(float x) { return 1.0f / (1.0f + expf(-x)); }
__device__ __forceinline__ float softplusf_(float x) { return log1pf(expf(x)); }

__device__ __forceinline__ float dot2f(uint32_t w, uint32_t a, float c) {
    asm("v_dot2_f32_f16 %0, %1, %2, %0" : "+v"(c) : "v"(w), "v"(a));
    return c;
}

// pair row map (144 pairs): k<32 -> wx row k (x); k in [32,288) -> wh row k-32 (h)
__device__ __forceinline__ float wvalA(const float* wx, const float* wh, int k, int col) {
    return (k < 32) ? wx[k * ZC + col] : wh[(k - 32) * ZC + col];
}
__device__ __forceinline__ uint32_t packA(const float* wx, const float* wh, int pr, int col) {
    __half2 h = __floats2half2_rn(wvalA(wx, wh, 2 * pr, col), wvalA(wx, wh, 2 * pr + 1, col));
    return *reinterpret_cast<uint32_t*>(&h);
}

// WG: u32 idx = (pr*256 + c)*4 + m -> col = 4c + m, pr 0..143.
// WrT: [1024 cols][12] u32 (reads pairs, q<10; wx rows 32..51), else 0.
// hw2: [128 up][92 col] u32.
__global__ __launch_bounds__(256) void prep_pack(const float* __restrict__ wx,
                                                 const float* __restrict__ wh,
                                                 const float* __restrict__ hw,
                                                 uint32_t* __restrict__ WG,
                                                 uint32_t* __restrict__ WrT,
                                                 uint32_t* __restrict__ hw2) {
    int idx = blockIdx.x * 256 + threadIdx.x;
    if (idx < 147456) {
        int m = idx & 3, c = (idx >> 2) & 255, pr = idx >> 10;
        WG[idx] = packA(wx, wh, pr, c * 4 + m);
    } else if (idx < 159744) {
        int q2 = idx - 147456;
        int col = q2 / 12, q = q2 - col * 12;
        if (q < 10) {
            __half2 h = __floats2half2_rn(wx[(32 + 2 * q) * ZC + col], wx[(33 + 2 * q) * ZC + col]);
            WrT[q2] = *reinterpret_cast<uint32_t*>(&h);
        } else WrT[q2] = 0u;
    } else if (idx < 171520) {
        int q3 = idx - 159744;
        int up = q3 / 92, col = q3 - up * 92;
        __half2 h = __floats2half2_rn(hw[(2 * up) * PC + col], hw[(2 * up + 1) * PC + col]);
        hw2[q3] = *reinterpret_cast<uint32_t*>(&h);
    }
}

// conv1 3x3 (1->16) SAME + relu + maxpool2
__global__ __launch_bounds__(256) void conv1_pool(const float* __restrict__ in,
                                                  const float* __restrict__ w,
                                                  const float* __restrict__ bias,
                                                  float* __restrict__ out) {
    int idx = blockIdx.x * 256 + threadIdx.x;
    if (idx >= 256 * 32 * 32 * 16) return;
    int c = idx & 15, x = (idx >> 4) & 31, y = (idx >> 9) & 31, b = idx >> 14;
    const float* inb = in + (size_t)b * 4096;
    float bv = bias[c];
    float mx = 0.0f;
    #pragma unroll
    for (int dy = 0; dy < 2; ++dy)
    #pragma unroll
    for (int dx = 0; dx < 2; ++dx) {
        int oy = 2 * y + dy, ox = 2 * x + dx;
        float s = bv;
        #pragma unroll
        for (int ky = 0; ky < 3; ++ky) {
            int iy = oy + ky - 1;
            if (iy < 0 || iy > 63) continue;
            #pragma unroll
            for (int kx = 0; kx < 3; ++kx) {
                int ix = ox + kx - 1;
                if (ix < 0 || ix > 63) continue;
                s = fmaf(inb[iy * 64 + ix], w[(ky * 3 + kx) * 16 + c], s);
            }
        }
        mx = fmaxf(mx, fmaxf(s, 0.0f));
    }
    out[idx] = mx;
}

// conv2 3x3 (16->32) SAME + relu + maxpool2
__global__ __launch_bounds__(256) void conv2_pool(const float* __restrict__ p1,
                                                  const float* __restrict__ w,
                                                  const float* __restrict__ bias,
                                                  float* __restrict__ seq) {
    int idx = blockIdx.x * 256 + threadIdx.x;
    if (idx >= 256 * 16 * 16 * 32) return;
    int c = idx & 31, x = (idx >> 5) & 15, y = (idx >> 9) & 15, b = idx >> 13;
    const float* pb = p1 + (size_t)b * (32 * 32 * 16);
    float bv = bias[c];
    float acc[4] = {bv, bv, bv, bv};
    #pragma unroll
    for (int ky = 0; ky < 3; ++ky)
    #pragma unroll
    for (int kx = 0; kx < 3; ++kx) {
        float w16[16];
        #pragma unroll
        for (int i = 0; i < 16; ++i) w16[i] = w[((ky * 3 + kx) * 16 + i) * 32 + c];
        #pragma unroll
        for (int dy = 0; dy < 2; ++dy)
        #pragma unroll
        for (int dx = 0; dx < 2; ++dx) {
            int iy = 2 * y + dy + ky - 1, ix = 2 * x + dx + kx - 1;
            if (iy < 0 || iy > 31 || ix < 0 || ix > 31) continue;
            const float4* pin4 = (const float4*)(pb + (iy * 32 + ix) * 16);
            float4 v0 = pin4[0], v1 = pin4[1], v2 = pin4[2], v3 = pin4[3];
            int a = dy * 2 + dx;
            acc[a] = fmaf(v0.x, w16[0], acc[a]);  acc[a] = fmaf(v0.y, w16[1], acc[a]);
            acc[a] = fmaf(v0.z, w16[2], acc[a]);  acc[a] = fmaf(v0.w, w16[3], acc[a]);
            acc[a] = fmaf(v1.x, w16[4], acc[a]);  acc[a] = fmaf(v1.y, w16[5], acc[a]);
            acc[a] = fmaf(v1.z, w16[6], acc[a]);  acc[a] = fmaf(v1.w, w16[7], acc[a]);
            acc[a] = fmaf(v2.x, w16[8], acc[a]);  acc[a] = fmaf(v2.y, w16[9], acc[a]);
            acc[a] = fmaf(v2.z, w16[10], acc[a]); acc[a] = fmaf(v2.w, w16[11], acc[a]);
            acc[a] = fmaf(v3.x, w16[12], acc[a]); acc[a] = fmaf(v3.y, w16[13], acc[a]);
            acc[a] = fmaf(v3.z, w16[14], acc[a]); acc[a] = fmaf(v3.w, w16[15], acc[a]);
        }
    }
    float mx = 0.0f;
    #pragma unroll
    for (int a = 0; a < 4; ++a) mx = fmaxf(mx, acc[a]);
    seq[idx] = mx;
}

// ---------------------------------------------------------------------------
// Persistent NTM scan, pipelined.
// ---------------------------------------------------------------------------
#define PSCLIP(b_, col_) fminf(fmaxf(pp[0][b_][col_] + pp[1][b_][col_] + pp[2][b_][col_] + pp[3][b_][col_] + hb[col_], -CLIPV), CLIPV)

#define DOT8(w_, a0_, a1_) \
    acc00 = dot2f(w_.x, a0_, acc00); acc01 = dot2f(w_.y, a0_, acc01); \
    acc02 = dot2f(w_.z, a0_, acc02); acc03 = dot2f(w_.w, a0_, acc03); \
    acc10 = dot2f(w_.x, a1_, acc10); acc11 = dot2f(w_.y, a1_, acc11); \
    acc12 = dot2f(w_.z, a1_, acc12); acc13 = dot2f(w_.w, a1_, acc13);

#define ISSUE(base_) { \
    const uint4* wp_ = WG4 + (size_t)(base_) * 256 + c; \
    pf0 = wp_[0];        pf1 = wp_[1 * 256];  pf2 = wp_[2 * 256];  pf3 = wp_[3 * 256]; \
    pf4 = wp_[4 * 256];  pf5 = wp_[5 * 256];  pf6 = wp_[6 * 256];  pf7 = wp_[7 * 256]; \
    pf8 = wp_[8 * 256];  pf9 = wp_[9 * 256]; }

#define CONSUME(base_) { \
    uint32_t a0_, a1_; \
    a0_ = ci2u0[(base_) + 0]; a1_ = ci2u1[(base_) + 0]; DOT8(pf0, a0_, a1_) \
    a0_ = ci2u0[(base_) + 1]; a1_ = ci2u1[(base_) + 1]; DOT8(pf1, a0_, a1_) \
    a0_ = ci2u0[(base_) + 2]; a1_ = ci2u1[(base_) + 2]; DOT8(pf2, a0_, a1_) \
    a0_ = ci2u0[(base_) + 3]; a1_ = ci2u1[(base_) + 3]; DOT8(pf3, a0_, a1_) \
    a0_ = ci2u0[(base_) + 4]; a1_ = ci2u1[(base_) + 4]; DOT8(pf4, a0_, a1_) \
    a0_ = ci2u0[(base_) + 5]; a1_ = ci2u1[(base_) + 5]; DOT8(pf5, a0_, a1_) \
    a0_ = ci2u0[(base_) + 6]; a1_ = ci2u1[(base_) + 6]; DOT8(pf6, a0_, a1_) \
    a0_ = ci2u0[(base_) + 7]; a1_ = ci2u1[(base_) + 7]; DOT8(pf7, a0_, a1_) \
    a0_ = ci2u0[(base_) + 8]; a1_ = ci2u1[(base_) + 8]; DOT8(pf8, a0_, a1_) \
    a0_ = ci2u0[(base_) + 9]; a1_ = ci2u1[(base_) + 9]; DOT8(pf9, a0_, a1_) }

__global__ __launch_bounds__(1024, 4) void ntm_scan8(
    const float* __restrict__ seq,
    const uint32_t* __restrict__ WG,
    const uint32_t* __restrict__ WrT,
    const uint32_t* __restrict__ hw2G,
    const float* __restrict__ lb,
    const float* __restrict__ hb,
    const float* __restrict__ ow,
    const float* __restrict__ ob,
    const float* __restrict__ dw,
    const float* __restrict__ db,
    float* __restrict__ out)          // [256][2]
{
    __shared__ uint4 Wl4[24 * 256];                   // 98304 B: resident pairs kq*36+30..35
    __shared__ float zpart[4][2][ZC];                 // 32768 B
    __shared__ __align__(16) _Float16 ci2h[2][320];   // 1280 B  (x 0..31, h 32..287, pad)
    __shared__ float Msh[2][MW][132];                 // 21120 B
    __shared__ float wprev[2][2][NLOC];               // 2048 B
    __shared__ float pp[4][2][PC];                    // 2944 B
    __shared__ float evs[2][MW], avs[2][MW];          // 320 B
    __shared__ float rds[2][MW];                      // 160 B
    __shared__ uint32_t rp[2][10];                    // 80 B
    __shared__ float o8[2][8];                        // 64 B
    // total ~159 KB

    const int t = threadIdx.x;
    const int bs0 = blockIdx.x * 2;
    const int kq = t >> 8, c = t & 255;
    const int prb = kq * 36;
    const uint4* WG4 = (const uint4*)WG;

    // ---- stage resident pairs (kq*36+30..35) ----
    for (int i = t; i < 6144; i += 1024) {
        int lkq = i / 1536, rem = i - lkq * 1536;
        int j = rem >> 8, cc = rem & 255;
        Wl4[i] = WG4[(lkq * 36 + 30 + j) * 256 + cc];
    }

    // ---- init state ----
    for (int i = t; i < 2 * 320; i += 1024) {
        int b = i / 320, k = i - b * 320;
        ci2h[b][k] = (k < 32) ? (_Float16)seq[(size_t)(bs0 + b) * 8192 + k] : (_Float16)0.0f;
    }
    for (int i = t; i < 2 * MW * 132; i += 1024) {
        int b = i / (MW * 132), r = i - b * (MW * 132);
        Msh[b][r / 132][r - (r / 132) * 132] = 1e-6f;
    }
    if (t < 512) {
        int b = t >> 8, r = t & 255;
        wprev[b][r >> 7][r & 127] = 1.0f / 128.0f;
    }
    if (t < 20) {
        __half2 h0 = __floats2half2_rn(1e-6f, 1e-6f);
        rp[t / 10][t % 10] = *reinterpret_cast<uint32_t*>(&h0);
    }
    float c_reg = 0.0f;   // cell state: thread t<512 owns (b=t>>8, u=t&255)
    __syncthreads();

    const uint32_t* ci2u0 = (const uint32_t*)&ci2h[0][0];
    const uint32_t* ci2u1 = (const uint32_t*)&ci2h[1][0];

    // ---- prologue: zpart for step 0 = Wx*x_0 (h=0; reads via WrT*rp in E) ----
    {
        float acc00 = 0, acc01 = 0, acc02 = 0, acc03 = 0;
        float acc10 = 0, acc11 = 0, acc12 = 0, acc13 = 0;
        if (kq == 0) {
            #pragma unroll
            for (int p = 0; p < 16; ++p) {
                uint4 wq = WG4[p * 256 + c];
                uint32_t a0 = ci2u0[p], a1 = ci2u1[p];
                DOT8(wq, a0, a1)
            }
        }
        *(float4*)&zpart[kq][0][4 * c] = make_float4(acc00, acc01, acc02, acc03);
        *(float4*)&zpart[kq][1][4 * c] = make_float4(acc10, acc11, acc12, acc13);
    }
    __syncthreads();

    uint4 pf0, pf1, pf2, pf3, pf4, pf5, pf6, pf7, pf8, pf9;

    for (int i = 0; i < 256; ++i) {
        // ---- region E: LSTM step i (+ x_{i+1} prefetch) ----
        if (t < 512) {
            int b = t >> 8, u = t & 255;
            uint32_t rp0 = rp[b][0], rp1 = rp[b][1], rp2 = rp[b][2], rp3 = rp[b][3];
            uint32_t rp4 = rp[b][4], rp5 = rp[b][5], rp6 = rp[b][6], rp7 = rp[b][7];
            uint32_t rp8 = rp[b][8], rp9 = rp[b][9];
            float zg4[4];
            #pragma unroll
            for (int g4 = 0; g4 < 4; ++g4) {
                const uint4* wp = (const uint4*)(WrT + ((g4 << 8) + u) * 12);
                uint4 A = wp[0], B = wp[1], C = wp[2];
                float s = 0.0f;
                s = dot2f(A.x, rp0, s); s = dot2f(A.y, rp1, s);
                s = dot2f(A.z, rp2, s); s = dot2f(A.w, rp3, s);
                s = dot2f(B.x, rp4, s); s = dot2f(B.y, rp5, s);
                s = dot2f(B.z, rp6, s); s = dot2f(B.w, rp7, s);
                s = dot2f(C.x, rp8, s); s = dot2f(C.y, rp9, s);
                zg4[g4] = s;
            }
            float zi = lb[u]       + zg4[0] + zpart[0][b][u]       + zpart[1][b][u]       + zpart[2][b][u]       + zpart[3][b][u];
            float zf = lb[256 + u] + zg4[1] + zpart[0][b][256 + u] + zpart[1][b][256 + u] + zpart[2][b][256 + u] + zpart[3][b][256 + u];
            float zg = lb[512 + u] + zg4[2] + zpart[0][b][512 + u] + zpart[1][b][512 + u] + zpart[2][b][512 + u] + zpart[3][b][512 + u];
            float zo = lb[768 + u] + zg4[3] + zpart[0][b][768 + u] + zpart[1][b][768 + u] + zpart[2][b][768 + u] + zpart[3][b][768 + u];
            float cg = sigmoidf_(zf) * c_reg + sigmoidf_(zi) * tanhf(zg);
            c_reg = cg;
            ci2h[b][32 + u] = (_Float16)(sigmoidf_(zo) * tanhf(cg));
        } else if (t < 576 && i < 255) {
            int q = t - 512, b = q >> 5, cc = q & 31;
            ci2h[b][cc] = (_Float16)seq[(size_t)(bs0 + b) * 8192 + (size_t)(i + 1) * 32 + cc];
        }
        __syncthreads();   // B-E

        // ---- region A: P3 head GEMM || issue chunk0 ----
        ISSUE(prb)
        if (t < 736) {
            int kq2 = t / 184, r = t - kq2 * 184, b = r / 92, col = r - b * 92;
            const uint32_t* hwp = hw2G + kq2 * 32 * 92 + col;
            const uint32_t* hbp = (b ? ci2u1 : ci2u0) + 16 + kq2 * 32;
            float s = 0.0f;
            #pragma unroll 8
            for (int uu = 0; uu < 32; ++uu)
                s = dot2f(hwp[uu * 92], hbp[uu], s);
            pp[kq2][b][col] = s;
        }
        __syncthreads();   // B-A

        float acc00 = 0, acc01 = 0, acc02 = 0, acc03 = 0;
        float acc10 = 0, acc11 = 0, acc12 = 0, acc13 = 0;

        // ---- region B: consume chunk0, issue chunk1 || P4 addressing ----
        CONSUME(prb)
        ISSUE(prb + 10)
        if (t < 256) {
            const int l = t & 63;
            const int b = t >> 7, hh = (t >> 6) & 1;
            const int hc = hh * 26;
            float beta  = softplusf_(PSCLIP(b, hc + 20));
            float g     = sigmoidf_(PSCLIP(b, hc + 21));
            float s0r = PSCLIP(b, hc + 22), s1r = PSCLIP(b, hc + 23), s2r = PSCLIP(b, hc + 24);
            float mS = fmaxf(s0r, fmaxf(s1r, s2r));
            float q0 = expf(s0r - mS), q1 = expf(s1r - mS), q2 = expf(s2r - mS);
            float qin = 1.0f / (q0 + q1 + q2);
            float sh0 = q0 * qin, sh1 = q1 * qin, sh2 = q2 * qin;
            float gamma = softplusf_(PSCLIP(b, hc + 25)) + 1.0f;

            float kvv = (l < 20) ? tanhf(PSCLIP(b, hc + l)) : 0.0f;
            float kn2 = kvv * kvv;
            #pragma unroll
            for (int o = 1; o < 64; o <<= 1) kn2 += __shfl_xor(kn2, o, 64);
            float kden = sqrtf(kn2) + 1e-8f;

            float d0 = 0, d1 = 0, m20 = 0, m21 = 0;
            #pragma unroll
            for (int wi = 0; wi < 20; ++wi) {
                float kk = __shfl(kvv, wi, 64);
                float2 mv = *reinterpret_cast<const float2*>(&Msh[b][wi][2 * l]);
                d0  = fmaf(kk, mv.x, d0);      d1  = fmaf(kk, mv.y, d1);
                m20 = fmaf(mv.x, mv.x, m20);   m21 = fmaf(mv.y, mv.y, m21);
            }
            float x0 = beta * (d0 / ((sqrtf(m20) + 1e-8f) * kden));
            float x1 = beta * (d1 / ((sqrtf(m21) + 1e-8f) * kden));
            float mx = fmaxf(x0, x1);
            #pragma unroll
            for (int o = 1; o < 64; o <<= 1) mx = fmaxf(mx, __shfl_xor(mx, o, 64));
            float e0 = expf(x0 - mx), e1 = expf(x1 - mx);
            float se = e0 + e1;
            #pragma unroll
            for (int o = 1; o < 64; o <<= 1) se += __shfl_xor(se, o, 64);
            float inv = 1.0f / se;
            float2 wpv = *reinterpret_cast<const float2*>(&wprev[b][hh][2 * l]);
            float wg0 = g * (e0 * inv) + (1.0f - g) * wpv.x;
            float wg1 = g * (e1 * inv) + (1.0f - g) * wpv.y;
            float wgm = __shfl(wg1, (l + 63) & 63, 64);
            float wgp = __shfl(wg0, (l + 1) & 63, 64);
            float wt0 = sh0 * wg1 + sh1 * wg0 + sh2 * wgm;
            float wt1 = sh0 * wgp + sh1 * wg1 + sh2 * wg0;
            float wpw0 = expf(gamma * logf(wt0 + 1e-8f));
            float wpw1 = expf(gamma * logf(wt1 + 1e-8f));
            float ssum = wpw0 + wpw1;
            #pragma unroll
            for (int o = 1; o < 64; o <<= 1) ssum += __shfl_xor(ssum, o, 64);
            float rin = 1.0f / ssum;
            *reinterpret_cast<float2*>(&wprev[b][hh][2 * l]) = make_float2(wpw0 * rin, wpw1 * rin);
        } else if (t < 336) {
            int q = t - 256, b = q / 40, r2 = q - b * 40;
            if (r2 < 20) evs[b][r2]      = sigmoidf_(PSCLIP(b, 52 + r2));
            else         avs[b][r2 - 20] = tanhf(PSCLIP(b, 72 + (r2 - 20)));
        }
        __syncthreads();   // B-B

        // ---- region C: consume chunk1, issue chunk2 || P5 fused read+write ----
        CONSUME(prb + 10)
        ISSUE(prb + 20)
        if (t < 320) {
            int grp = t >> 4;                 // (b, q) 16-lane group
            int b = grp / 10, q = grp - b * 10;
            int half = (t >> 3) & 1, l8 = t & 7;
            int wi = 2 * q + half;
            int n0 = l8 * 16;
            float evb = evs[b][wi], avb = avs[b][wi];
            float s = 0.0f;
            #pragma unroll
            for (int n = n0; n < n0 + 16; ++n) {
                float m = Msh[b][wi][n];
                s = fmaf(wprev[b][0][n], m, s);
                float ww = wprev[b][1][n];
                Msh[b][wi][n] = m * (1.0f - ww * evb) + ww * avb;
            }
            s += __shfl_xor(s, 1, 64); s += __shfl_xor(s, 2, 64); s += __shfl_xor(s, 4, 64);
            float rodd = __shfl_xor(s, 8, 64);
            if ((t & 15) == 0) {
                rds[b][2 * q] = s; rds[b][2 * q + 1] = rodd;
                __half2 hp = __floats2half2_rn(s, rodd);
                rp[b][q] = *reinterpret_cast<uint32_t*>(&hp);
            }
        }
        __syncthreads();   // B-C

        // ---- region D: consume chunk2 + resident pairs + write zpart ----
        CONSUME(prb + 20)
        #pragma unroll
        for (int j = 0; j < 6; ++j) {
            uint4 wj = Wl4[(kq * 6 + j) * 256 + c];
            uint32_t a0 = ci2u0[prb + 30 + j], a1 = ci2u1[prb + 30 + j];
            DOT8(wj, a0, a1)
        }
        *(float4*)&zpart[kq][0][4 * c] = make_float4(acc00, acc01, acc02, acc03);
        *(float4*)&zpart[kq][1][4 * c] = make_float4(acc10, acc11, acc12, acc13);
        __syncthreads();   // B-D
    }

    // ---- final NTM output head + dense + softmax ----
    if (t < 16) {
        int b = t >> 3, o = t & 7;
        float s = ob[o];
        for (int u = 0; u < 256; ++u) s = fmaf((float)ci2h[b][32 + u], ow[u * 8 + o], s);
        #pragma unroll
        for (int wi = 0; wi < 20; ++wi) s = fmaf(rds[b][wi], ow[(256 + wi) * 8 + o], s);
        o8[b][o] = fminf(fmaxf(s, -CLIPV), CLIPV);
    }
    __syncthreads();
    if (t < 2) {
        float l0 = db[0], l1 = db[1];
        #pragma unroll
        for (int k = 0; k < 8; ++k) {
            float v = o8[t][k];
            l0 = fmaf(v, dw[k * 2 + 0], l0);
            l1 = fmaf(v, dw[k * 2 + 1], l1);
        }
        float m = fmaxf(l0, l1);
        float q0 = expf(l0 - m), q1 = expf(l1 - m);
        float inv = 1.0f / (q0 + q1);
        out[(bs0 + t) * 2 + 0] = q0 * inv;
        out[(bs0 + t) * 2 + 1] = q1 * inv;
    }
}

extern "C" void kernel_launch(void* const* d_in, const int* in_sizes, int n_in,
                              void* d_out, int out_size, void* d_ws, size_t ws_size,
                              hipStream_t stream) {
    const float* inputs = (const float*)d_in[0];
    const float* c1w = (const float*)d_in[1];
    const float* c1b = (const float*)d_in[2];
    const float* c2w = (const float*)d_in[3];
    const float* c2b = (const float*)d_in[4];
    const float* lwx = (const float*)d_in[5];
    const float* lwh = (const float*)d_in[6];
    const float* lb  = (const float*)d_in[7];
    const float* hw  = (const float*)d_in[8];
    const float* hb  = (const float*)d_in[9];
    const float* ow  = (const float*)d_in[10];
    const float* ob  = (const float*)d_in[11];
    const float* dw  = (const float*)d_in[12];
    const float* db  = (const float*)d_in[13];
    float* out = (float*)d_out;

    float* ws  = (float*)d_ws;
    float* p1  = ws;                             // 4,194,304 f
    float* seq = ws + 4194304;                   // 2,097,152 f
    uint32_t* WG   = (uint32_t*)(ws + 6291456);  // 147,456 u32
    uint32_t* WrT  = WG + 147456;                //  12,288 u32
    uint32_t* hw2G = WrT + 12288;                //  11,776 u32

    hipLaunchKernelGGL(prep_pack,  dim3(670),   dim3(256),  0, stream, lwx, lwh, hw, WG, WrT, hw2G);
    hipLaunchKernelGGL(conv1_pool, dim3(16384), dim3(256),  0, stream, inputs, c1w, c1b, p1);
    hipLaunchKernelGGL(conv2_pool, dim3(8192),  dim3(256),  0, stream, p1, c2w, c2b, seq);
    hipLaunchKernelGGL(ntm_scan8,  dim3(128),   dim3(1024), 0, stream,
                       seq, WG, WrT, hw2G, lb, hb, ow, ob, dw, db, out);
}

// Round 9
// 5749.424 us; speedup vs baseline: 1.1157x; 1.1157x over previous
//
#include <hip/hip_runtime.h>
#include <hip/hip_fp16.h>
#include <cstdint>
#include <cstddef>

// ---------------------------------------------------------------------------
// CNN (conv1+pool, conv2+pool) -> seq [256][256][32]
// NTM scan: 128 blocks x 1024 threads, 2 batch/block, 1 block/CU.
// 3 barriers per step:
//  E: LSTM (3 zparts + WrT*rp reads-term) -> h_i ; x_{i+1} prefetch
//  A: t<768: z-GEMM pairs 0..23 of each K-third (5 LDS-resident + 19 streamed)
//     t 768..951: P3 head GEMM full-K per column -> final clipped ps
//  X: t<768: z-GEMM pairs 24..47 + zpart write
//     t>=768 (4 waves, one per (b,head)): P4 addressing + P5 read / erase-add
//     on DOUBLE-BUFFERED M (read Msh[i&1], write Msh[(i+1)&1]) - no hazard.
// Only 8 accumulator floats live across a barrier (A->X). No bulk register
// state across barriers (R3/R4/R8 lesson: allocator spills it).
// ci pair slots (u32): [x:0..15][h:16..143], 144 pairs.
// ---------------------------------------------------------------------------

#define MW    20
#define NLOC  128
#define ZC    1024
#define PC    92
#define CLIPV 20.0f

__device__ __forceinline__ float sigmoidf_(float x) { return 1.0f / (1.0f + expf(-x)); }
__device__ __forceinline__ float softplusf_(float x) { return log1pf(expf(x)); }

__device__ __forceinline__ float dot2f(uint32_t w, uint32_t a, float c) {
    asm("v_dot2_f32_f16 %0, %1, %2, %0" : "+v"(c) : "v"(w), "v"(a));
    return c;
}

// pair row map (144 pairs): k<32 -> wx row k (x); k in [32,288) -> wh row k-32 (h)
__device__ __forceinline__ float wvalA(const float* wx, const float* wh, int k, int col) {
    return (k < 32) ? wx[k * ZC + col] : wh[(k - 32) * ZC + col];
}
__device__ __forceinline__ uint32_t packA(const float* wx, const float* wh, int pr, int col) {
    __half2 h = __floats2half2_rn(wvalA(wx, wh, 2 * pr, col), wvalA(wx, wh, 2 * pr + 1, col));
    return *reinterpret_cast<uint32_t*>(&h);
}

// WG: u32 idx = (pr*256 + c)*4 + m -> col = 4c + m, pr 0..143.
// WrT: [1024 cols][12] u32 (reads pairs q<10: wx rows 32..51), else 0.
// hw2: [128 up][92 col] u32.
__global__ __launch_bounds__(256) void prep_pack(const float* __restrict__ wx,
                                                 const float* __restrict__ wh,
                                                 const float* __restrict__ hw,
                                                 uint32_t* __restrict__ WG,
                                                 uint32_t* __restrict__ WrT,
                                                 uint32_t* __restrict__ hw2) {
    int idx = blockIdx.x * 256 + threadIdx.x;
    if (idx < 147456) {
        int m = idx & 3, c = (idx >> 2) & 255, pr = idx >> 10;
        WG[idx] = packA(wx, wh, pr, c * 4 + m);
    } else if (idx < 159744) {
        int q2 = idx - 147456;
        int col = q2 / 12, q = q2 - col * 12;
        if (q < 10) {
            __half2 h = __floats2half2_rn(wx[(32 + 2 * q) * ZC + col], wx[(33 + 2 * q) * ZC + col]);
            WrT[q2] = *reinterpret_cast<uint32_t*>(&h);
        } else WrT[q2] = 0u;
    } else if (idx < 171520) {
        int q3 = idx - 159744;
        int up = q3 / 92, col = q3 - up * 92;
        __half2 h = __floats2half2_rn(hw[(2 * up) * PC + col], hw[(2 * up + 1) * PC + col]);
        hw2[q3] = *reinterpret_cast<uint32_t*>(&h);
    }
}

// conv1 3x3 (1->16) SAME + relu + maxpool2
__global__ __launch_bounds__(256) void conv1_pool(const float* __restrict__ in,
                                                  const float* __restrict__ w,
                                                  const float* __restrict__ bias,
                                                  float* __restrict__ out) {
    int idx = blockIdx.x * 256 + threadIdx.x;
    if (idx >= 256 * 32 * 32 * 16) return;
    int c = idx & 15, x = (idx >> 4) & 31, y = (idx >> 9) & 31, b = idx >> 14;
    const float* inb = in + (size_t)b * 4096;
    float bv = bias[c];
    float mx = 0.0f;
    #pragma unroll
    for (int dy = 0; dy < 2; ++dy)
    #pragma unroll
    for (int dx = 0; dx < 2; ++dx) {
        int oy = 2 * y + dy, ox = 2 * x + dx;
        float s = bv;
        #pragma unroll
        for (int ky = 0; ky < 3; ++ky) {
            int iy = oy + ky - 1;
            if (iy < 0 || iy > 63) continue;
            #pragma unroll
            for (int kx = 0; kx < 3; ++kx) {
                int ix = ox + kx - 1;
                if (ix < 0 || ix > 63) continue;
                s = fmaf(inb[iy * 64 + ix], w[(ky * 3 + kx) * 16 + c], s);
            }
        }
        mx = fmaxf(mx, fmaxf(s, 0.0f));
    }
    out[idx] = mx;
}

// conv2 3x3 (16->32) SAME + relu + maxpool2
__global__ __launch_bounds__(256) void conv2_pool(const float* __restrict__ p1,
                                                  const float* __restrict__ w,
                                                  const float* __restrict__ bias,
                                                  float* __restrict__ seq) {
    int idx = blockIdx.x * 256 + threadIdx.x;
    if (idx >= 256 * 16 * 16 * 32) return;
    int c = idx & 31, x = (idx >> 5) & 15, y = (idx >> 9) & 15, b = idx >> 13;
    const float* pb = p1 + (size_t)b * (32 * 32 * 16);
    float bv = bias[c];
    float acc[4] = {bv, bv, bv, bv};
    #pragma unroll
    for (int ky = 0; ky < 3; ++ky)
    #pragma unroll
    for (int kx = 0; kx < 3; ++kx) {
        float w16[16];
        #pragma unroll
        for (int i = 0; i < 16; ++i) w16[i] = w[((ky * 3 + kx) * 16 + i) * 32 + c];
        #pragma unroll
        for (int dy = 0; dy < 2; ++dy)
        #pragma unroll
        for (int dx = 0; dx < 2; ++dx) {
            int iy = 2 * y + dy + ky - 1, ix = 2 * x + dx + kx - 1;
            if (iy < 0 || iy > 31 || ix < 0 || ix > 31) continue;
            const float4* pin4 = (const float4*)(pb + (iy * 32 + ix) * 16);
            float4 v0 = pin4[0], v1 = pin4[1], v2 = pin4[2], v3 = pin4[3];
            int a = dy * 2 + dx;
            acc[a] = fmaf(v0.x, w16[0], acc[a]);  acc[a] = fmaf(v0.y, w16[1], acc[a]);
            acc[a] = fmaf(v0.z, w16[2], acc[a]);  acc[a] = fmaf(v0.w, w16[3], acc[a]);
            acc[a] = fmaf(v1.x, w16[4], acc[a]);  acc[a] = fmaf(v1.y, w16[5], acc[a]);
            acc[a] = fmaf(v1.z, w16[6], acc[a]);  acc[a] = fmaf(v1.w, w16[7], acc[a]);
            acc[a] = fmaf(v2.x, w16[8], acc[a]);  acc[a] = fmaf(v2.y, w16[9], acc[a]);
            acc[a] = fmaf(v2.z, w16[10], acc[a]); acc[a] = fmaf(v2.w, w16[11], acc[a]);
            acc[a] = fmaf(v3.x, w16[12], acc[a]); acc[a] = fmaf(v3.y, w16[13], acc[a]);
            acc[a] = fmaf(v3.z, w16[14], acc[a]); acc[a] = fmaf(v3.w, w16[15], acc[a]);
        }
    }
    float mx = 0.0f;
    #pragma unroll
    for (int a = 0; a < 4; ++a) mx = fmaxf(mx, acc[a]);
    seq[idx] = mx;
}

// ---------------------------------------------------------------------------
// Persistent NTM scan, 3 barriers/step.
// ---------------------------------------------------------------------------
#define DOT8A(w_, a0_, a1_) \
    a00 = dot2f(w_.x, a0_, a00); a01 = dot2f(w_.y, a0_, a01); \
    a02 = dot2f(w_.z, a0_, a02); a03 = dot2f(w_.w, a0_, a03); \
    a10 = dot2f(w_.x, a1_, a10); a11 = dot2f(w_.y, a1_, a11); \
    a12 = dot2f(w_.z, a1_, a12); a13 = dot2f(w_.w, a1_, a13);

__global__ __launch_bounds__(1024, 4) void ntm_scan9(
    const float* __restrict__ seq,
    const uint32_t* __restrict__ WG,
    const uint32_t* __restrict__ WrT,
    const uint32_t* __restrict__ hw2G,
    const float* __restrict__ lb,
    const float* __restrict__ hb,
    const float* __restrict__ ow,
    const float* __restrict__ ob,
    const float* __restrict__ dw,
    const float* __restrict__ db,
    float* __restrict__ out)          // [256][2]
{
    __shared__ uint4 Wl4[15 * 256];                   // 61440 B (5 pairs per K-third)
    __shared__ float zpart[3][2][ZC];                 // 24576 B
    __shared__ __align__(16) _Float16 ci2h[2][320];   // 1280 B (x pairs 0..15, h 16..143)
    __shared__ float Msh[2][2][MW][132];              // 42240 B (double-buffered M)
    __shared__ float wprev[2][2][NLOC];               // 2048 B
    __shared__ float ps[2][PC];                       // 736 B
    __shared__ float rds[2][MW];                      // 160 B
    __shared__ uint32_t rp[2][10];                    // 80 B
    __shared__ float o8[2][8];                        // 64 B
    // total ~132.6 KB -> 1 block/CU

    const int t = threadIdx.x;
    const int bs0 = blockIdx.x * 2;
    const uint4* WG4 = (const uint4*)WG;

    // ---- stage resident pairs: per K-third ks, pairs ks*48 + 0..4 ----
    for (int i = t; i < 3840; i += 1024) {
        int lp = i >> 8, cc = i & 255;
        int pr = (lp / 5) * 48 + (lp % 5);
        Wl4[i] = WG4[pr * 256 + cc];
    }

    // ---- init state ----
    for (int i = t; i < 2 * 320; i += 1024) {
        int b = i / 320, k = i - b * 320;
        ci2h[b][k] = (k < 32) ? (_Float16)seq[(size_t)(bs0 + b) * 8192 + k] : (_Float16)0.0f;
    }
    for (int i = t; i < 2 * 2 * MW * 132; i += 1024) {
        int p = i / (2 * MW * 132), r = i - p * (2 * MW * 132);
        int b = r / (MW * 132), r2 = r - b * (MW * 132);
        Msh[p][b][r2 / 132][r2 - (r2 / 132) * 132] = 1e-6f;
    }
    if (t < 512) {
        int b = t >> 8, r = t & 255;
        wprev[b][r >> 7][r & 127] = 1.0f / 128.0f;
    }
    if (t < 20) {
        __half2 h0 = __floats2half2_rn(1e-6f, 1e-6f);
        rp[t / 10][t % 10] = *reinterpret_cast<uint32_t*>(&h0);
    }
    float c_reg = 0.0f;   // cell state: thread t<512 owns (b=t>>8, u=t&255)
    __syncthreads();

    const uint32_t* ci2u0 = (const uint32_t*)&ci2h[0][0];
    const uint32_t* ci2u1 = (const uint32_t*)&ci2h[1][0];

    const int ks = t >> 8;         // K-third 0..2 (t<768)
    const int c  = t & 255;        // col group 4c..4c+3
    const int prb = ks * 48;

    // ---- prologue: zpart = Wx*x_0 (h=0; reads-term added via WrT*rp in E) ----
    {
        float a00 = 0, a01 = 0, a02 = 0, a03 = 0;
        float a10 = 0, a11 = 0, a12 = 0, a13 = 0;
        if (t < 768) {
            if (ks == 0) {
                #pragma unroll
                for (int p = 0; p < 16; ++p) {
                    uint4 wq = WG4[p * 256 + c];
                    uint32_t x0 = ci2u0[p], x1 = ci2u1[p];
                    DOT8A(wq, x0, x1)
                }
            }
            *(float4*)&zpart[ks][0][4 * c] = make_float4(a00, a01, a02, a03);
            *(float4*)&zpart[ks][1][4 * c] = make_float4(a10, a11, a12, a13);
        }
    }
    __syncthreads();

    for (int i = 0; i < 256; ++i) {
        // ================= region E: LSTM step i =================
        if (t < 512) {
            int b = t >> 8, u = t & 255;
            uint32_t rp0 = rp[b][0], rp1 = rp[b][1], rp2 = rp[b][2], rp3 = rp[b][3];
            uint32_t rp4 = rp[b][4], rp5 = rp[b][5], rp6 = rp[b][6], rp7 = rp[b][7];
            uint32_t rp8 = rp[b][8], rp9 = rp[b][9];
            float zg4[4];
            #pragma unroll
            for (int g4 = 0; g4 < 4; ++g4) {
                const uint4* wp = (const uint4*)(WrT + ((g4 << 8) + u) * 12);
                uint4 A = wp[0], B = wp[1], C = wp[2];
                float s = 0.0f;
                s = dot2f(A.x, rp0, s); s = dot2f(A.y, rp1, s);
                s = dot2f(A.z, rp2, s); s = dot2f(A.w, rp3, s);
                s = dot2f(B.x, rp4, s); s = dot2f(B.y, rp5, s);
                s = dot2f(B.z, rp6, s); s = dot2f(B.w, rp7, s);
                s = dot2f(C.x, rp8, s); s = dot2f(C.y, rp9, s);
                zg4[g4] = s;
            }
            float zi = lb[u]       + zg4[0] + zpart[0][b][u]       + zpart[1][b][u]       + zpart[2][b][u];
            float zf = lb[256 + u] + zg4[1] + zpart[0][b][256 + u] + zpart[1][b][256 + u] + zpart[2][b][256 + u];
            float zg = lb[512 + u] + zg4[2] + zpart[0][b][512 + u] + zpart[1][b][512 + u] + zpart[2][b][512 + u];
            float zo = lb[768 + u] + zg4[3] + zpart[0][b][768 + u] + zpart[1][b][768 + u] + zpart[2][b][768 + u];
            float cg = sigmoidf_(zf) * c_reg + sigmoidf_(zi) * tanhf(zg);
            c_reg = cg;
            ci2h[b][32 + u] = (_Float16)(sigmoidf_(zo) * tanhf(cg));
        } else if (t < 576 && i < 255) {
            int q = t - 512, b = q >> 5, cc = q & 31;
            ci2h[b][cc] = (_Float16)seq[(size_t)(bs0 + b) * 8192 + (size_t)(i + 1) * 32 + cc];
        }
        __syncthreads();   // B1

        float a00 = 0, a01 = 0, a02 = 0, a03 = 0;
        float a10 = 0, a11 = 0, a12 = 0, a13 = 0;

        // ================= region A =================
        if (t < 768) {
            if (i < 255) {
                #pragma unroll
                for (int j = 0; j < 5; ++j) {            // resident pairs
                    uint4 wq = Wl4[(ks * 5 + j) * 256 + c];
                    uint32_t x0 = ci2u0[prb + j], x1 = ci2u1[prb + j];
                    DOT8A(wq, x0, x1)
                }
                #pragma unroll
                for (int p = 5; p < 24; ++p) {           // streamed
                    uint4 wq = WG4[(prb + p) * 256 + c];
                    uint32_t x0 = ci2u0[prb + p], x1 = ci2u1[prb + p];
                    DOT8A(wq, x0, x1)
                }
            }
        } else if (t < 952) {
            // P3: one column of head params, full K (128 u-pairs), 2 accumulators
            int g = t - 768, b = g / PC, col = g - b * PC;
            const uint32_t* hu = (b ? ci2u1 : ci2u0) + 16;
            const uint32_t* hp = hw2G + col;
            float s0 = 0.0f, s1 = 0.0f;
            #pragma unroll 16
            for (int up = 0; up < 128; up += 2) {
                s0 = dot2f(hp[up * PC], hu[up], s0);
                s1 = dot2f(hp[(up + 1) * PC], hu[up + 1], s1);
            }
            ps[b][col] = fminf(fmaxf(s0 + s1 + hb[col], -CLIPV), CLIPV);
        }
        __syncthreads();   // B2

        // ================= region X =================
        if (t < 768) {
            if (i < 255) {
                #pragma unroll
                for (int p = 24; p < 48; ++p) {
                    uint4 wq = WG4[(prb + p) * 256 + c];
                    uint32_t x0 = ci2u0[prb + p], x1 = ci2u1[prb + p];
                    DOT8A(wq, x0, x1)
                }
                *(float4*)&zpart[ks][0][4 * c] = make_float4(a00, a01, a02, a03);
                *(float4*)&zpart[ks][1][4 * c] = make_float4(a10, a11, a12, a13);
            }
        } else {
            // ---- P4 + P5, one wave per (b, head); lane owns n = 2l, 2l+1 ----
            const int g = t - 768;
            const int b = g >> 7, hh = (g >> 6) & 1, l = g & 63;
            const int hc = hh * 26;
            const int par = i & 1;
            float beta  = softplusf_(ps[b][hc + 20]);
            float gte   = sigmoidf_(ps[b][hc + 21]);
            float s0r = ps[b][hc + 22], s1r = ps[b][hc + 23], s2r = ps[b][hc + 24];
            float mS = fmaxf(s0r, fmaxf(s1r, s2r));
            float q0 = expf(s0r - mS), q1 = expf(s1r - mS), q2 = expf(s2r - mS);
            float qin = 1.0f / (q0 + q1 + q2);
            float sh0 = q0 * qin, sh1 = q1 * qin, sh2 = q2 * qin;
            float gamma = softplusf_(ps[b][hc + 25]) + 1.0f;

            float kvv = (l < 20) ? tanhf(ps[b][hc + l]) : 0.0f;
            float kn2 = kvv * kvv;
            #pragma unroll
            for (int o = 1; o < 64; o <<= 1) kn2 += __shfl_xor(kn2, o, 64);
            float kden = sqrtf(kn2) + 1e-8f;

            float d0 = 0, d1 = 0, m20 = 0, m21 = 0;
            #pragma unroll
            for (int wi = 0; wi < 20; ++wi) {
                float kk = __shfl(kvv, wi, 64);
                float2 mv = *reinterpret_cast<const float2*>(&Msh[par][b][wi][2 * l]);
                d0  = fmaf(kk, mv.x, d0);      d1  = fmaf(kk, mv.y, d1);
                m20 = fmaf(mv.x, mv.x, m20);   m21 = fmaf(mv.y, mv.y, m21);
            }
            float x0 = beta * (d0 / ((sqrtf(m20) + 1e-8f) * kden));
            float x1 = beta * (d1 / ((sqrtf(m21) + 1e-8f) * kden));
            float mx = fmaxf(x0, x1);
            #pragma unroll
            for (int o = 1; o < 64; o <<= 1) mx = fmaxf(mx, __shfl_xor(mx, o, 64));
            float e0 = expf(x0 - mx), e1 = expf(x1 - mx);
            float se = e0 + e1;
            #pragma unroll
            for (int o = 1; o < 64; o <<= 1) se += __shfl_xor(se, o, 64);
            float inv = 1.0f / se;
            float2 wpv = *reinterpret_cast<const float2*>(&wprev[b][hh][2 * l]);
            float wg0 = gte * (e0 * inv) + (1.0f - gte) * wpv.x;
            float wg1 = gte * (e1 * inv) + (1.0f - gte) * wpv.y;
            float wgm = __shfl(wg1, (l + 63) & 63, 64);
            float wgp = __shfl(wg0, (l + 1) & 63, 64);
            float wt0 = sh0 * wg1 + sh1 * wg0 + sh2 * wgm;
            float wt1 = sh0 * wgp + sh1 * wg1 + sh2 * wg0;
            float wpw0 = expf(gamma * logf(wt0 + 1e-8f));
            float wpw1 = expf(gamma * logf(wt1 + 1e-8f));
            float ssum = wpw0 + wpw1;
            #pragma unroll
            for (int o = 1; o < 64; o <<= 1) ssum += __shfl_xor(ssum, o, 64);
            float rin = 1.0f / ssum;
            float wn0 = wpw0 * rin, wn1 = wpw1 * rin;
            *reinterpret_cast<float2*>(&wprev[b][hh][2 * l]) = make_float2(wn0, wn1);

            if (hh == 0) {
                // ---- P5 read: r = w_read . M_old ----
                float rr[20];
                #pragma unroll
                for (int wi = 0; wi < 20; ++wi) {
                    float2 mv = *reinterpret_cast<const float2*>(&Msh[par][b][wi][2 * l]);
                    float s = fmaf(wn0, mv.x, wn1 * mv.y);
                    #pragma unroll
                    for (int o = 1; o < 64; o <<= 1) s += __shfl_xor(s, o, 64);
                    rr[wi] = s;
                    if (l == wi) rds[b][wi] = s;
                }
                #pragma unroll
                for (int q = 0; q < 10; ++q) {
                    __half2 hp = __floats2half2_rn(rr[2 * q], rr[2 * q + 1]);
                    uint32_t pq = *reinterpret_cast<uint32_t*>(&hp);
                    if (l == q) rp[b][q] = pq;
                }
            } else {
                // ---- P5 write: erase + add into the other M buffer ----
                float evr = 0.0f, avr = 0.0f;
                if (l < 20) { evr = sigmoidf_(ps[b][52 + l]); avr = tanhf(ps[b][72 + l]); }
                #pragma unroll
                for (int wi = 0; wi < 20; ++wi) {
                    float evb = __shfl(evr, wi, 64), avb = __shfl(avr, wi, 64);
                    float2 mv = *reinterpret_cast<const float2*>(&Msh[par][b][wi][2 * l]);
                    float n0 = mv.x * (1.0f - wn0 * evb) + wn0 * avb;
                    float n1 = mv.y * (1.0f - wn1 * evb) + wn1 * avb;
                    *reinterpret_cast<float2*>(&Msh[par ^ 1][b][wi][2 * l]) = make_float2(n0, n1);
                }
            }
        }
        __syncthreads();   // B3
    }

    // ---- final NTM output head + dense + softmax ----
    if (t < 16) {
        int b = t >> 3, o = t & 7;
        float s = ob[o];
        for (int u = 0; u < 256; ++u) s = fmaf((float)ci2h[b][32 + u], ow[u * 8 + o], s);
        #pragma unroll
        for (int wi = 0; wi < 20; ++wi) s = fmaf(rds[b][wi], ow[(256 + wi) * 8 + o], s);
        o8[b][o] = fminf(fmaxf(s, -CLIPV), CLIPV);
    }
    __syncthreads();
    if (t < 2) {
        float l0 = db[0], l1 = db[1];
        #pragma unroll
        for (int k = 0; k < 8; ++k) {
            float v = o8[t][k];
            l0 = fmaf(v, dw[k * 2 + 0], l0);
            l1 = fmaf(v, dw[k * 2 + 1], l1);
        }
        float m = fmaxf(l0, l1);
        float q0 = expf(l0 - m), q1 = expf(l1 - m);
        float inv = 1.0f / (q0 + q1);
        out[(bs0 + t) * 2 + 0] = q0 * inv;
        out[(bs0 + t) * 2 + 1] = q1 * inv;
    }
}

extern "C" void kernel_launch(void* const* d_in, const int* in_sizes, int n_in,
                              void* d_out, int out_size, void* d_ws, size_t ws_size,
                              hipStream_t stream) {
    const float* inputs = (const float*)d_in[0];
    const float* c1w = (const float*)d_in[1];
    const float* c1b = (const float*)d_in[2];
    const float* c2w = (const float*)d_in[3];
    const float* c2b = (const float*)d_in[4];
    const float* lwx = (const float*)d_in[5];
    const float* lwh = (const float*)d_in[6];
    const float* lb  = (const float*)d_in[7];
    const float* hw  = (const float*)d_in[8];
    const float* hb  = (const float*)d_in[9];
    const float* ow  = (const float*)d_in[10];
    const float* ob  = (const float*)d_in[11];
    const float* dw  = (const float*)d_in[12];
    const float* db  = (const float*)d_in[13];
    float* out = (float*)d_out;

    float* ws  = (float*)d_ws;
    float* p1  = ws;                             // 4,194,304 f
    float* seq = ws + 4194304;                   // 2,097,152 f
    uint32_t* WG   = (uint32_t*)(ws + 6291456);  // 147,456 u32
    uint32_t* WrT  = WG + 147456;                //  12,288 u32
    uint32_t* hw2G = WrT + 12288;                //  11,776 u32

    hipLaunchKernelGGL(prep_pack,  dim3(670),   dim3(256),  0, stream, lwx, lwh, hw, WG, WrT, hw2G);
    hipLaunchKernelGGL(conv1_pool, dim3(16384), dim3(256),  0, stream, inputs, c1w, c1b, p1);
    hipLaunchKernelGGL(conv2_pool, dim3(8192),  dim3(256),  0, stream, p1, c2w, c2b, seq);
    hipLaunchKernelGGL(ntm_scan9,  dim3(128),   dim3(1024), 0, stream,
                       seq, WG, WrT, hw2G, lb, hb, ow, ob, dw, db, out);
}